// Round 3
// baseline (169.999 us; speedup 1.0000x reference)
//
#include <hip/hip_runtime.h>
#include <math.h>

// Block DCT (8x8, stride 8) + soft histogram (121 sigmoid thresholds, gamma=1e6).
// gamma=1e6 makes the sigmoid a step function except within ~3e-5 of an integer
// threshold; exp(-1e6)==0.0f exactly in fp32, so only the two thresholds
// adjacent to a coefficient can be non-saturated -> exact histogram with a
// rare sigmoid slow path (R2 measured absmax == 0.0 vs the jax reference).
//
// R3 structure: ONE dispatch, no memset, no global atomics.
//   grid = 16 WGs (one per batch) x 1024 threads (16 waves).
//   Each thread owns one 8x8 block (1024 blocks per batch).
//   LDS histogram, 2 copies (copy = lane>>5) to halve same-address atomic
//   serialization within a wave-op; stride 121 (odd) keeps merge reads
//   conflict-free. Each WG exclusively writes out[b] -> plain stores, all
//   7680 values, so the 0xAA-poisoned d_out needs no pre-zeroing.

#define HSTRIDE 121                    // bins 0..120 tracked; 0..119 emitted
#define HCOPY   (64 * HSTRIDE)         // 7744 floats per histogram copy

__global__ __launch_bounds__(1024) void dct_hist_kernel(
    const float* __restrict__ in,     // [16][256][256][1]
    const float* __restrict__ basis,  // [8][8][1][64]
    float* __restrict__ out)          // [16][120][64][1]
{
    __shared__ float hist[2 * HCOPY];  // 61952 B

    const int t = threadIdx.x;         // 0..1023
    const int b = blockIdx.x;          // batch 0..15

    // ---- zero both LDS histogram copies ----
    for (int i = t; i < 2 * HCOPY; i += 1024) hist[i] = 0.0f;

    // ---- recover 1D DCT matrix C[a][x] (wave-uniform -> SGPRs) ----
    // basis flat index (x*8 + y)*64 + k, k = 8u+v. Take y=0, k=8a:
    // basis[x][0][8a] = C[a,x] * C[0,0], C[0,0] = 1/sqrt(8).
    float Cm[8][8];
    #pragma unroll
    for (int a = 0; a < 8; ++a)
        #pragma unroll
        for (int x = 0; x < 8; ++x)
            Cm[a][x] = basis[x * 512 + a * 8] * 2.8284271247461903f;

    __syncthreads();

    // ---- load this thread's 8x8 block; row pass (identical fmaf order to R2) ----
    const int by = t >> 5;             // block-row 0..31
    const int bx = t & 31;             // block-col 0..31
    const float* p0 = in + ((b * 256 + by * 8) * 256 + bx * 8);

    float tv[8][8];  // tv[x][v] = sum_y C[v][y] * p[x][y]
    #pragma unroll
    for (int x = 0; x < 8; ++x) {
        const float4 r0 = *(const float4*)(p0 + x * 256);
        const float4 r1 = *(const float4*)(p0 + x * 256 + 4);
        const float p[8] = {r0.x, r0.y, r0.z, r0.w, r1.x, r1.y, r1.z, r1.w};
        #pragma unroll
        for (int v = 0; v < 8; ++v) {
            float s = 0.0f;
            #pragma unroll
            for (int y = 0; y < 8; ++y) s = fmaf(Cm[v][y], p[y], s);
            tv[x][v] = s;
        }
    }

    // ---- column pass + histogram ----
    float* h = hist + ((t & 32) ? HCOPY : 0);  // copy by lane>>5: 32-way max collision
    const float EPS = 3e-5f;  // |gamma*d| > 30 -> sigmoid saturated in fp32
    #pragma unroll
    for (int u = 0; u < 8; ++u) {
        #pragma unroll
        for (int v = 0; v < 8; ++v) {
            float xv = 0.0f;
            #pragma unroll
            for (int x = 0; x < 8; ++x) xv = fmaf(Cm[u][x], tv[x][v], xv);
            const int k = u * 8 + v;

            const int j = (int)floorf(xv + 60.0f);  // threshold j-60 just below x
            if (j >= -1 && j <= 120) {
                const float bf  = (float)j - 60.0f;
                const float dlo = xv - bf;
                const float dhi = xv - (bf + 1.0f);
                if (dlo > EPS && dhi < -EPS) {
                    // fast path: both adjacent sigmoids fully saturated
                    if (j >= 0 && j <= 119) atomicAdd(&h[k * HSTRIDE + j], 1.0f);
                } else {
                    // slow path: exact sigmoid at the (at most one) live threshold
                    const float slo = 1.0f / (1.0f + expf(-1e6f * dlo));
                    const float shi = 1.0f / (1.0f + expf(-1e6f * dhi));
                    if (j >= 0 && j <= 119)     atomicAdd(&h[k * HSTRIDE + j],     slo - shi);
                    if (j - 1 >= 0)             atomicAdd(&h[k * HSTRIDE + j - 1], 1.0f - slo);
                    if (j + 1 <= 119)           atomicAdd(&h[k * HSTRIDE + j + 1], shi);
                }
            }
        }
    }

    __syncthreads();

    // ---- exclusive write-out: out[b][bin][k] = (copy0 + copy1) / 1024 ----
    // idx -> (bin = idx>>6, k = idx&63); stores coalesced over k.
    // LDS read addr k*121+bin: banks (25k+bin)&31, 2-way across 64 lanes = free.
    float* outb = out + b * (120 * 64);
    for (int idx = t; idx < 120 * 64; idx += 1024) {
        const int bin = idx >> 6;
        const int k   = idx & 63;
        outb[idx] = (hist[k * HSTRIDE + bin] + hist[HCOPY + k * HSTRIDE + bin])
                    * (1.0f / 1024.0f);
    }
}

extern "C" void kernel_launch(void* const* d_in, const int* in_sizes, int n_in,
                              void* d_out, int out_size, void* d_ws, size_t ws_size,
                              hipStream_t stream) {
    const float* inputs = (const float*)d_in[0];  // [16,256,256,1] fp32
    const float* basis  = (const float*)d_in[1];  // [8,8,1,64] fp32
    float* out = (float*)d_out;                   // [16,120,64,1] fp32

    dct_hist_kernel<<<dim3(16), dim3(1024), 0, stream>>>(inputs, basis, out);
}

// Round 8
// 71.883 us; speedup vs baseline: 2.3649x; 2.3649x over previous
//
#include <hip/hip_runtime.h>
#include <math.h>

// CONTROL RESUBMISSION of the exact R2-passing source (72.45 us, absmax 0.0).
// R4-R7 all died with "MI355X container failed twice" on a restructured
// kernel; this bit-identical known-good source disambiguates infra outage
// (this also fails) from kernel-family toxicity (this passes).
//
// Block DCT (8x8, stride 8) + soft histogram (121 sigmoid thresholds, gamma=1e6).
// gamma=1e6 makes the sigmoid a step function except within ~3e-5 of an
// integer threshold; exp(-1e6)==0.0f exactly in fp32, so only the two
// thresholds adjacent to each coefficient can be non-saturated -> exact
// histogram with a rare sigmoid slow path.
//
// Layout: one thread per 8x8 block (16384 blocks). Grid 256 WGs x 64 threads:
// WG = (batch b, slice q) covering block-rows 2q, 2q+1 (64 blocks).
// Separable DCT: 1D basis C recovered from the provided 2D basis input
// (basis[x][0][8a] = C[a,x]*C[0,0], C[0,0] = 1/sqrt(8)).
// LDS histogram hist[k][121] (stride 121: odd -> conflict-free merge reads),
// merged into d_out with skip-zero global float atomics, /1024 folded in.

#define HSTRIDE 121  // bins 0..120 tracked; only 0..119 merged (x5 has 120 bins)

__global__ __launch_bounds__(64) void dct_hist_kernel(
    const float* __restrict__ in,     // [16][256][256][1]
    const float* __restrict__ basis,  // [8][8][1][64]
    float* __restrict__ out)          // [16][120][64][1], pre-zeroed
{
    __shared__ float hist[64 * HSTRIDE];  // 30976 B

    const int t  = threadIdx.x;       // 0..63
    const int wg = blockIdx.x;        // 0..255
    const int b  = wg >> 4;           // batch 0..15
    const int q  = wg & 15;           // slice 0..15 -> block-rows 2q, 2q+1

    // ---- zero LDS histogram ----
    #pragma unroll
    for (int i = 0; i < HSTRIDE; ++i) hist[i * 64 + t] = 0.0f;
    __syncthreads();

    // ---- recover 1D DCT matrix C[a][x] from 2D basis (wave-uniform loads) ----
    // basis flat index (x*8 + y)*64 + k, k = 8u+v. Take y=0, k=8a:
    // basis[x][0][8a] = C[a,x] * C[0,0],  C[0,0] = 1/sqrt(8).
    float Cm[8][8];
    #pragma unroll
    for (int a = 0; a < 8; ++a)
        #pragma unroll
        for (int x = 0; x < 8; ++x)
            Cm[a][x] = basis[x * 512 + a * 8] * 2.8284271247461903f;

    // ---- load this thread's 8x8 block and do the row pass ----
    const int by = q * 2 + (t >> 5);      // block-row 0..31
    const int bx = t & 31;                // block-col 0..31
    const float* p0 = in + ((b * 256 + by * 8) * 256 + bx * 8);

    float tv[8][8];  // tv[x][v] = sum_y C[v][y] * p[x][y]
    #pragma unroll
    for (int x = 0; x < 8; ++x) {
        const float4 r0 = *(const float4*)(p0 + x * 256);
        const float4 r1 = *(const float4*)(p0 + x * 256 + 4);
        const float p[8] = {r0.x, r0.y, r0.z, r0.w, r1.x, r1.y, r1.z, r1.w};
        #pragma unroll
        for (int v = 0; v < 8; ++v) {
            float s = 0.0f;
            #pragma unroll
            for (int y = 0; y < 8; ++y) s = fmaf(Cm[v][y], p[y], s);
            tv[x][v] = s;
        }
    }

    // ---- column pass + histogram, one coefficient at a time ----
    const float EPS = 3e-5f;  // |gamma*d| > 30 -> sigmoid saturated in fp32
    #pragma unroll
    for (int u = 0; u < 8; ++u) {
        #pragma unroll
        for (int v = 0; v < 8; ++v) {
            float xv = 0.0f;
            #pragma unroll
            for (int x = 0; x < 8; ++x) xv = fmaf(Cm[u][x], tv[x][v], xv);
            const int k = u * 8 + v;

            const int j = (int)floorf(xv + 60.0f);  // bin index (threshold j-60 below x)
            if (j >= -1 && j <= 120) {
                const float bf  = (float)j - 60.0f;
                const float dlo = xv - bf;           // in (-eps, 1+eps)
                const float dhi = xv - (bf + 1.0f);  // matches reference's x - bin rounding
                if (dlo > EPS && dhi < -EPS) {
                    // fast path: both adjacent sigmoids saturated
                    if (j >= 0 && j <= 119) atomicAdd(&hist[k * HSTRIDE + j], 1.0f);
                } else {
                    // slow path: exact sigmoid at the (at most one) live threshold
                    const float slo = 1.0f / (1.0f + expf(-1e6f * dlo));
                    const float shi = 1.0f / (1.0f + expf(-1e6f * dhi));
                    if (j >= 0 && j <= 119)     atomicAdd(&hist[k * HSTRIDE + j],     slo - shi);
                    if (j - 1 >= 0)             atomicAdd(&hist[k * HSTRIDE + j - 1], 1.0f - slo);
                    if (j + 1 <= 119)           atomicAdd(&hist[k * HSTRIDE + j + 1], shi);
                }
            }
        }
    }

    __syncthreads();

    // ---- merge LDS histogram into global output (thread t owns coef k=t) ----
    // out[b][bin][k], + = sum over the 16 slice-WGs of this batch; /1024 folded in.
    float* outb = out + b * (120 * 64);
    for (int bin = 0; bin < 120; ++bin) {
        const float v = hist[t * HSTRIDE + bin];
        if (v != 0.0f) atomicAdd(&outb[bin * 64 + t], v * (1.0f / 1024.0f));
    }
}

extern "C" void kernel_launch(void* const* d_in, const int* in_sizes, int n_in,
                              void* d_out, int out_size, void* d_ws, size_t ws_size,
                              hipStream_t stream) {
    const float* inputs = (const float*)d_in[0];  // [16,256,256,1] fp32
    const float* basis  = (const float*)d_in[1];  // [8,8,1,64] fp32
    float* out = (float*)d_out;                   // [16,120,64,1] fp32

    // harness poisons d_out with 0xAA before every launch -> zero it first
    (void)hipMemsetAsync(out, 0, (size_t)out_size * sizeof(float), stream);

    dct_hist_kernel<<<dim3(256), dim3(64), 0, stream>>>(inputs, basis, out);
}